// Round 1
// baseline (458.909 us; speedup 1.0000x reference)
//
#include <hip/hip_runtime.h>
#include <hip/hip_bf16.h>

// Attention_50946902065218: Bahdanau-style attention
// B=256, L=196, E=2048, D=1024, A=512
// Pipeline:
//  k_wepack: We fp32 -> bf16, packed per-K-step-contiguous [kb][n][k'] (ws)
//  k_bias2 : bias2[b][a] = be[a] + bd[a] + dec[b]@Wd[:,a]                (ws)
//  k_gemm_score: scores[b*196+l] = sum_a wf[a]*tanh((enc@We)[m,a]+bias2) (ws)
//  k_softmax: mask + softmax over L -> alpha (d_out part 2)
//  k_awe   : awe[b,e] = sum_l alpha[b,l]*enc[b,l,e]  (d_out part 1)

#define B_ 256
#define L_ 196
#define E_ 2048
#define D_ 1024
#define A_ 512
#define M_TOT (B_ * L_)   // 50176 = 784 * 64

typedef __attribute__((ext_vector_type(8))) short bf16x8;
typedef __attribute__((ext_vector_type(4))) float f32x4;

static __device__ __forceinline__ unsigned short f2bf(float f) {
    union { float f; unsigned u; } u{f};
    unsigned r = u.u + 0x7fffu + ((u.u >> 16) & 1u);   // RNE
    return (unsigned short)(r >> 16);
}

// ---------------- kernel 0a: pack We (E x A fp32) -> WeP bf16 -----------------
// WeP layout: [kb][n][k'] with kb = k/32, k' = k%32  (so each K-step's 32KB
// B-slice is one contiguous block; kernel-1 staging is a linear copy)
__global__ __launch_bounds__(256) void k_wepack(const float* __restrict__ We,
                                                unsigned short* __restrict__ WeP) {
    int i = blockIdx.x * 256 + threadIdx.x;       // source index over 2048*512
    int k = i >> 9, n = i & 511;
    WeP[((k >> 5) << 14) + (n << 5) + (k & 31)] = f2bf(We[i]);
}

// ---------------- kernel 0b: bias2 = be + bd + dec @ Wd ----------------------
__global__ __launch_bounds__(256) void k_bias2(const float* __restrict__ dec,
                                               const float* __restrict__ Wd,
                                               const float* __restrict__ be,
                                               const float* __restrict__ bd,
                                               float* __restrict__ bias2) {
    int b = blockIdx.x, t = threadIdx.x;
    __shared__ float ds[D_];
    for (int i = t; i < D_; i += 256) ds[i] = dec[b * D_ + i];
    __syncthreads();
    for (int a0 = 0; a0 < A_; a0 += 256) {
        int a = a0 + t;
        float acc = 0.f;
        #pragma unroll 8
        for (int d = 0; d < D_; d++) acc += ds[d] * Wd[d * A_ + a];
        bias2[b * A_ + a] = acc + be[a] + bd[a];
    }
}

// ---------------- kernel 1: fused GEMM + tanh + wf-dot -----------------------
// grid 784 blocks, each handles 64 rows of M (flattened b*196+l), all 512 cols.
// 512 threads = 8 waves (2 M x 4 N). Per wave: 32 rows x 128 cols.
__global__ __launch_bounds__(512) void k_gemm_score(
        const float* __restrict__ enc,
        const unsigned short* __restrict__ WeP,
        const float* __restrict__ bias2,
        const float* __restrict__ wf,
        float* __restrict__ scores) {
    __shared__ __align__(16) unsigned short a_lds[64 * 48];   // 6 KB (stride 48 = pad)
    __shared__ __align__(16) unsigned short b_lds[512 * 48];  // 48 KB
    __shared__ float score_lds[64];

    const int tid = threadIdx.x;
    const int m0 = blockIdx.x * 64;
    const int lane = tid & 63;
    const int wid = tid >> 6;
    const int wm = wid >> 2, wn = wid & 3;
    const int kg = lane >> 4, lr = lane & 15;

    // A staging: thread -> (row ar, 4 cols at akc)
    const int ar = tid >> 3;
    const int akc = (tid & 7) << 2;
    const float* aptr = enc + (size_t)(m0 + ar) * E_ + akc;
    // B staging: thread -> row n=tid of the current K-slice (32 bf16 = 64B)
    const unsigned short* bptr = WeP + ((size_t)tid << 5);

    f32x4 acc[2][8];
    #pragma unroll
    for (int i = 0; i < 2; i++)
        #pragma unroll
        for (int j = 0; j < 8; j++) acc[i][j] = (f32x4){0.f, 0.f, 0.f, 0.f};

    for (int kb = 0; kb < 64; kb++) {
        // --- stage A (fp32 -> bf16) ---
        float4 av = *reinterpret_cast<const float4*>(aptr + kb * 32);
        short4 ap;
        ap.x = (short)f2bf(av.x); ap.y = (short)f2bf(av.y);
        ap.z = (short)f2bf(av.z); ap.w = (short)f2bf(av.w);
        *reinterpret_cast<short4*>(&a_lds[ar * 48 + akc]) = ap;
        // --- stage B (linear 32KB copy) ---
        const uint4* bsrc = reinterpret_cast<const uint4*>(bptr + ((size_t)kb << 14));
        uint4 b0 = bsrc[0], b1 = bsrc[1], b2 = bsrc[2], b3 = bsrc[3];
        uint4* bdst = reinterpret_cast<uint4*>(&b_lds[tid * 48]);
        bdst[0] = b0; bdst[1] = b1; bdst[2] = b2; bdst[3] = b3;
        __syncthreads();

        // --- fragments + MFMA ---
        bf16x8 af[2];
        #pragma unroll
        for (int i = 0; i < 2; i++)
            af[i] = *reinterpret_cast<const bf16x8*>(
                &a_lds[(wm * 32 + i * 16 + lr) * 48 + kg * 8]);
        bf16x8 bfr[8];
        #pragma unroll
        for (int j = 0; j < 8; j++)
            bfr[j] = *reinterpret_cast<const bf16x8*>(
                &b_lds[(wn * 128 + j * 16 + lr) * 48 + kg * 8]);
        #pragma unroll
        for (int i = 0; i < 2; i++)
            #pragma unroll
            for (int j = 0; j < 8; j++)
                acc[i][j] = __builtin_amdgcn_mfma_f32_16x16x32_bf16(
                    af[i], bfr[j], acc[i][j], 0, 0, 0);
        __syncthreads();
    }

    // --- epilogue: tanh + wf dot, reduce over cols ---
    if (tid < 64) score_lds[tid] = 0.f;
    __syncthreads();
    #pragma unroll
    for (int i = 0; i < 2; i++) {
        #pragma unroll
        for (int r = 0; r < 4; r++) {
            int R = wm * 32 + i * 16 + kg * 4 + r;   // C/D: col=lane&15, row=(lane>>4)*4+reg
            int gm = m0 + R;
            int bg = gm / L_;
            float sum = 0.f;
            #pragma unroll
            for (int j = 0; j < 8; j++) {
                int C = wn * 128 + j * 16 + lr;
                float x = acc[i][j][r] + bias2[bg * A_ + C];
                sum += wf[C] * tanhf(x);
            }
            #pragma unroll
            for (int mk = 1; mk < 16; mk <<= 1) sum += __shfl_xor(sum, mk);
            if (lr == 0) atomicAdd(&score_lds[R], sum);
        }
    }
    __syncthreads();
    if (tid < 64) scores[m0 + tid] = score_lds[tid];
}

// ---------------- kernel 2: mask + softmax over L ----------------------------
__global__ __launch_bounds__(256) void k_softmax(const float* __restrict__ scores,
                                                 const int* __restrict__ mask,
                                                 const float* __restrict__ bfp,
                                                 float* __restrict__ alpha) {
    int b = blockIdx.x, t = threadIdx.x;
    float bfv = bfp[0];
    float v = -INFINITY;
    if (t < L_) v = (mask[b * L_ + t] == 0) ? -1e9f : (scores[b * L_ + t] + bfv);
    __shared__ float redm[4], reds[4];
    float m = v;
    #pragma unroll
    for (int s = 1; s < 64; s <<= 1) m = fmaxf(m, __shfl_xor(m, s));
    int w = t >> 6;
    if ((t & 63) == 0) redm[w] = m;
    __syncthreads();
    m = fmaxf(fmaxf(redm[0], redm[1]), fmaxf(redm[2], redm[3]));
    float e = (t < L_) ? expf(v - m) : 0.f;
    float s = e;
    #pragma unroll
    for (int k = 1; k < 64; k <<= 1) s += __shfl_xor(s, k);
    if ((t & 63) == 0) reds[w] = s;
    __syncthreads();
    s = reds[0] + reds[1] + reds[2] + reds[3];
    if (t < L_) alpha[b * L_ + t] = e / s;
}

// ---------------- kernel 3: awe = sum_l alpha * enc --------------------------
// grid (8 e-chunks of 256, 256 batches), 64 threads, 1 float4/thread
__global__ __launch_bounds__(64) void k_awe(const float* __restrict__ enc,
                                            const float* __restrict__ alpha,
                                            float* __restrict__ awe) {
    int b = blockIdx.y, ec = blockIdx.x, t = threadIdx.x;
    __shared__ float al[L_];
    for (int l = t; l < L_; l += 64) al[l] = alpha[b * L_ + l];
    __syncthreads();
    int e0 = (ec << 8) + (t << 2);
    const float* base = enc + (size_t)b * L_ * E_ + e0;
    float4 acc = {0.f, 0.f, 0.f, 0.f};
    #pragma unroll 4
    for (int l = 0; l < L_; l++) {
        float4 v = *reinterpret_cast<const float4*>(base + (size_t)l * E_);
        float a = al[l];
        acc.x += a * v.x; acc.y += a * v.y; acc.z += a * v.z; acc.w += a * v.w;
    }
    *reinterpret_cast<float4*>(awe + b * E_ + e0) = acc;
}

extern "C" void kernel_launch(void* const* d_in, const int* in_sizes, int n_in,
                              void* d_out, int out_size, void* d_ws, size_t ws_size,
                              hipStream_t stream) {
    const float* enc  = (const float*)d_in[0];
    const float* dec  = (const float*)d_in[1];
    const int*   mask = (const int*)d_in[2];
    const float* We   = (const float*)d_in[3];
    const float* be   = (const float*)d_in[4];
    const float* Wd   = (const float*)d_in[5];
    const float* bd   = (const float*)d_in[6];
    const float* wf   = (const float*)d_in[7];
    const float* bf   = (const float*)d_in[8];

    float* awe   = (float*)d_out;                  // [256][2048]
    float* alpha = awe + (size_t)B_ * E_;          // [256][196]

    char* ws = (char*)d_ws;
    unsigned short* WeP = (unsigned short*)ws;                       // 2 MB
    float* bias2  = (float*)(ws + (2u << 20));                       // 512 KB
    float* scores = (float*)(ws + (2u << 20) + (512u << 10));        // 200 KB

    hipLaunchKernelGGL(k_wepack, dim3((E_ * A_) / 256), dim3(256), 0, stream, We, WeP);
    hipLaunchKernelGGL(k_bias2, dim3(B_), dim3(256), 0, stream, dec, Wd, be, bd, bias2);
    hipLaunchKernelGGL(k_gemm_score, dim3(M_TOT / 64), dim3(512), 0, stream,
                       enc, WeP, bias2, wf, scores);
    hipLaunchKernelGGL(k_softmax, dim3(B_), dim3(256), 0, stream, scores, mask, bf, alpha);
    hipLaunchKernelGGL(k_awe, dim3(8, B_), dim3(64), 0, stream, enc, alpha, awe);
}